// Round 1
// 325.967 us; speedup vs baseline: 1.0089x; 1.0089x over previous
//
#include <hip/hip_runtime.h>

#define NN 512
#define CC 1024
#define OO 256
#define VV 68
#define PP 7
#define NC (NN*CC)
#define NV_CNT 34816.0f   // N*T*V = 512*68

typedef float floatx4 __attribute__((ext_vector_type(4)));

__device__ __forceinline__ int part_of(int v){
  return (v>=17)+(v>=22)+(v>=27)+(v>=36)+(v>=42)+(v>=48);
}

// K0: repack w1 [o][c] -> w1p[cb][o] (float4 units), coalesced read.
__global__ __launch_bounds__(256) void k0_prep(const float* __restrict__ w1,
    float* __restrict__ w1p){
  int g = blockIdx.x*256 + threadIdx.x;          // f4 idx in w1: g = o*256+cb
  int o = g >> 8, cb = g & 255;
  float4 v = ((const float4*)w1)[g];
  ((float4*)w1p)[cb*256 + o] = v;
}

// K1: streaming part-sum. 4096 blocks x 128 rows. Coalesced f4 loads ->
// LDS transpose stg[v][row] (stride 129). 256 threads reduce half-rows
// (34 v each), combine via LDS.
// NOTE: the v-loop is specialized on wave-uniform `half` so that after
// unrolling, v (and thus part_of(v)) is a compile-time constant. This keeps
// s[]/q2[] statically indexed -> VGPRs, NOT scratch (rule: runtime-indexed
// arrays go to scratch). Accumulation order per part is unchanged (bit-exact).
__global__ __launch_bounds__(256) void k1_partsum(const float* __restrict__ x,
    float* __restrict__ S, float* __restrict__ S2){
  __shared__ float stg[68*129];                  // 35088 B; later reused as hs/hq
  int R = blockIdx.x*128;                        // first row of block
  const float4* src = (const float4*)(x + (size_t)R*VV);
  #pragma unroll
  for (int k=0;k<9;k++){
    int g = k*256 + threadIdx.x;                 // f4 idx in [0,2176)
    if (k==8 && threadIdx.x>=128) break;
    float4 v4 = src[g];
    int row = g/17, q = g - row*17;
    stg[(q*4+0)*129 + row] = v4.x;
    stg[(q*4+1)*129 + row] = v4.y;
    stg[(q*4+2)*129 + row] = v4.z;
    stg[(q*4+3)*129 + row] = v4.w;
  }
  __syncthreads();

  int row  = threadIdx.x & 127;
  int half = threadIdx.x >> 7;                   // 0: v<34, 1: v>=34 (wave-uniform)
  float s[PP], q2[PP];
  #pragma unroll
  for (int p=0;p<PP;p++){ s[p]=0.f; q2[p]=0.f; }
  if (half==0){
    #pragma unroll
    for (int v=0; v<34; v++){
      int p = part_of(v);                        // constant-folds after unroll
      float e = stg[v*129 + row];
      s[p] += e;
      q2[p] = fmaf(e, e, q2[p]);
    }
  } else {
    #pragma unroll
    for (int v=34; v<68; v++){
      int p = part_of(v);                        // constant-folds after unroll
      float e = stg[v*129 + row];
      s[p] += e;
      q2[p] = fmaf(e, e, q2[p]);
    }
  }
  __syncthreads();                               // stg reads done
  float* hs = stg;                               // reuse: 128*7
  float* hq = stg + 128*PP;                      // 128*7
  if (half==1){
    #pragma unroll
    for (int p=0;p<PP;p++){ hs[row*PP+p]=s[p]; hq[row*PP+p]=q2[p]; }
  }
  __syncthreads();
  if (half==0){
    int r = R + row;
    #pragma unroll
    for (int p=0;p<PP;p++){
      S [p*NC + r] = s[p]  + hs[row*PP+p];
      S2[p*NC + r] = q2[p] + hq[row*PP+p];
    }
  }
}

// K2: per n (512 blocks): stage S row (28KB LDS), o x c GEMM (wave-uniform
// LDS broadcasts, w1p from L2), softmax, BN partials (S from LDS, S2 from
// coalesced global). LDS ~37KB -> 4 blocks/CU, 4 waves/SIMD.
__global__ __launch_bounds__(256) void k2_att(const float* __restrict__ S,
    const float* __restrict__ S2, const float* __restrict__ w1p,
    const float* __restrict__ b1, const float* __restrict__ w2,
    const float* __restrict__ b2, float* __restrict__ att,
    float* __restrict__ partial){
  int n = blockIdx.x;
  int t = threadIdx.x;

  __shared__ float4 sSf4[PP*256];                // 28672 B: S[p][c] this n
  __shared__ float hred[2048];                   // 8192 B
  __shared__ float red_s[4][PP], red_m[4][PP], pre[PP], att_s[PP];
  float* sSl = (float*)sSf4;                     // [p*1024 + c]

  for (int u = t; u < PP*256; u += 256){
    int p = u >> 8, cb = u & 255;
    sSf4[u] = *(const float4*)(S + (size_t)p*NC + (size_t)n*CC + cb*4);
  }
  __syncthreads();

  // GEMM acc[k][p] = sum_{c slice} S[c,p] * w1[o=k*32+oh, c]
  int oh = t & 31, ch = t >> 5;
  float acc[8][PP];
  #pragma unroll
  for (int k=0;k<8;k++)
    #pragma unroll
    for (int p=0;p<PP;p++) acc[k][p] = 0.f;

  const float4* wp = (const float4*)w1p;
  for (int i=0;i<32;i++){
    int gcb = ch*32 + i;
    const float4* wrow = wp + (size_t)gcb*256 + oh;
    float4 w[8];
    #pragma unroll
    for (int k=0;k<8;k++) w[k] = wrow[32*k];
    #pragma unroll
    for (int p=0;p<PP;p++){
      float4 sv = sSf4[p*256 + gcb];             // 2 addrs/wave broadcast
      #pragma unroll
      for (int k=0;k<8;k++){
        acc[k][p] = fmaf(w[k].x, sv.x, acc[k][p]);
        acc[k][p] = fmaf(w[k].y, sv.y, acc[k][p]);
        acc[k][p] = fmaf(w[k].z, sv.z, acc[k][p]);
        acc[k][p] = fmaf(w[k].w, sv.w, acc[k][p]);
      }
    }
  }

  // reduce over ch, mean/max over o, softmax over p
  const float inv_cnt[PP] = {1.f/17.f,1.f/5.f,1.f/5.f,1.f/9.f,1.f/6.f,1.f/6.f,1.f/20.f};
  float bo = b1[t];
  float h[PP];
  #pragma unroll
  for (int p=0;p<PP;p++){
    __syncthreads();
    #pragma unroll
    for (int k=0;k<8;k++) hred[ch*256 + k*32 + oh] = acc[k][p];
    __syncthreads();
    float hs = 0.f;
    #pragma unroll
    for (int c8=0;c8<8;c8++) hs += hred[c8*256 + t];
    h[p] = fmaf(hs, inv_cnt[p], bo);
  }

  int lane = t & 63, wid = t >> 6;
  #pragma unroll
  for (int p=0;p<PP;p++){
    float sm = h[p], mx = h[p];
    #pragma unroll
    for (int off=32; off>0; off>>=1){
      sm += __shfl_down(sm, off, 64);
      mx = fmaxf(mx, __shfl_down(mx, off, 64));
    }
    if (lane==0){ red_s[wid][p]=sm; red_m[wid][p]=mx; }
  }
  __syncthreads();
  if (t < PP){
    int p = t;
    float sm = red_s[0][p]+red_s[1][p]+red_s[2][p]+red_s[3][p];
    float mx = fmaxf(fmaxf(red_m[0][p],red_m[1][p]),
                     fmaxf(red_m[2][p],red_m[3][p]));
    pre[p] = w2[0]*(sm*(1.f/(float)OO)) + w2[1]*mx + b2[0];
  }
  __syncthreads();
  if (t == 0){
    float m = pre[0];
    #pragma unroll
    for (int p=1;p<PP;p++) m = fmaxf(m, pre[p]);
    float e[PP], sum=0.f;
    #pragma unroll
    for (int p=0;p<PP;p++){ e[p] = expf(pre[p]-m); sum += e[p]; }
    float inv = 1.f/sum;
    #pragma unroll
    for (int p=0;p<PP;p++){
      float a = e[p]*inv;
      att_s[p] = a;
      att[n*PP+p] = a;
    }
  }
  __syncthreads();

  // BN partials: sm from LDS S, sq from global S2 (coalesced dword loads)
  float a[PP], a2[PP];
  #pragma unroll
  for (int p=0;p<PP;p++){ a[p] = att_s[p]; a2[p] = a[p]*a[p]; }
  const float* S2n = S2 + (size_t)n*CC;
  #pragma unroll
  for (int j=0;j<4;j++){
    int c = j*256 + t;
    float sm=0.f, sq=0.f;
    #pragma unroll
    for (int p=0;p<PP;p++){
      sm = fmaf(a[p],  sSl[p*1024 + c],   sm);
      sq = fmaf(a2[p], S2n[(size_t)p*NC + c], sq);
    }
    partial[n*2048 + c]        = sm;
    partial[n*2048 + 1024 + c] = sq;
  }
}

// K3b: single-dispatch reduce over n + BN finalize. 32 blocks x 256 thr.
__global__ __launch_bounds__(256) void k3b_finalize(const float* __restrict__ partial,
    const float* __restrict__ gamma, const float* __restrict__ beta,
    float* __restrict__ scsh){
  __shared__ float rs[8][32], rq[8][32];
  int cl = threadIdx.x & 31, grp = threadIdx.x >> 5;
  int c = blockIdx.x*32 + cl;
  float sm=0.f, sq=0.f;
  for (int i=0;i<64;i++){
    int n = grp*64 + i;
    sm += partial[n*2048 + c];
    sq += partial[n*2048 + 1024 + c];
  }
  rs[grp][cl] = sm; rq[grp][cl] = sq;
  __syncthreads();
  if (threadIdx.x < 32){
    float tsm=0.f, tsq=0.f;
    #pragma unroll
    for (int g=0; g<8; g++){ tsm += rs[g][threadIdx.x]; tsq += rq[g][threadIdx.x]; }
    int cc = blockIdx.x*32 + threadIdx.x;
    float mean = tsm * (1.0f/NV_CNT);
    float var  = tsq * (1.0f/NV_CNT) - mean*mean;
    float rstd = rsqrtf(var + 1e-5f);
    float sc = gamma[cc]*rstd;
    scsh[cc]        = sc;
    scsh[1024 + cc] = beta[cc] - mean*sc;
  }
}

// K4: out = relu( x*(att_j*sc + 1) + sh ); nontemporal stores via ext_vector.
__global__ __launch_bounds__(256) void k4_out(const float* __restrict__ x,
    const float* __restrict__ att, const float* __restrict__ scsh,
    float* __restrict__ out){
  int f = blockIdx.x*256 + threadIdx.x;          // float4 index, < NC*17
  int n = blockIdx.x / 68;                       // uniform within block
  __shared__ float s_att[PP];
  if (threadIdx.x < PP) s_att[threadIdx.x] = att[n*PP + threadIdx.x];
  __syncthreads();
  int r = f/17;
  int q = f - r*17;
  int v0 = q*4;
  int c = r & (CC-1);
  float4 xv = ((const float4*)x)[f];
  float sc = scsh[c];
  float sh = scsh[1024 + c];
  float vals[4];
  #pragma unroll
  for (int j=0;j<4;j++){
    int p = part_of(v0 + j);
    float a = s_att[p];
    float e = (j==0)?xv.x:(j==1)?xv.y:(j==2)?xv.z:xv.w;
    vals[j] = fmaxf(fmaf(e, fmaf(a, sc, 1.0f), sh), 0.0f);
  }
  floatx4 ov; ov.x=vals[0]; ov.y=vals[1]; ov.z=vals[2]; ov.w=vals[3];
  __builtin_nontemporal_store(ov, ((floatx4*)out) + f);
}

extern "C" void kernel_launch(void* const* d_in, const int* in_sizes, int n_in,
                              void* d_out, int out_size, void* d_ws, size_t ws_size,
                              hipStream_t stream) {
  const float* x     = (const float*)d_in[0];
  const float* w1    = (const float*)d_in[1];
  const float* b1    = (const float*)d_in[2];
  const float* w2    = (const float*)d_in[3];
  const float* b2    = (const float*)d_in[4];
  const float* gamma = (const float*)d_in[5];
  const float* beta  = (const float*)d_in[6];
  float* out = (float*)d_out;

  float* w1p     = (float*)d_ws;                 // 256*1024 (1 MB)
  float* S       = w1p + OO*CC;                  // 7*NC (14 MB)
  float* S2      = S + 7*NC;                     // 7*NC (14 MB)
  float* partial = S2 + 7*NC;                    // 512*2048 (4 MB)
  float* scsh    = partial + NN*2048;            // 2048
  float* att     = scsh + 2048;                  // 512*7
  // ~33 MB of ws; every buffer fully overwritten each call

  k0_prep     <<<256,         256, 0, stream>>>(w1, w1p);
  k1_partsum  <<<NC/128,      256, 0, stream>>>(x, S, S2);
  k2_att      <<<NN,          256, 0, stream>>>(S, S2, w1p, b1, w2, b2, att, partial);
  k3b_finalize<<<32,          256, 0, stream>>>(partial, gamma, beta, scsh);
  k4_out      <<<(NC*17)/256, 256, 0, stream>>>(x, att, scsh, out);
}

// Round 2
// 314.954 us; speedup vs baseline: 1.0442x; 1.0350x over previous
//
#include <hip/hip_runtime.h>

#define NN 512
#define CC 1024
#define OO 256
#define VV 68
#define PP 7
#define NC (NN*CC)
#define NV_CNT 34816.0f   // N*T*V = 512*68

typedef float floatx4 __attribute__((ext_vector_type(4)));

__device__ __forceinline__ int part_of(int v){
  return (v>=17)+(v>=22)+(v>=27)+(v>=36)+(v>=42)+(v>=48);
}

// K0: repack w1 [o][c] -> w1p[cb][o] (float4 units), coalesced read.
__global__ __launch_bounds__(256) void k0_prep(const float* __restrict__ w1,
    float* __restrict__ w1p){
  int g = blockIdx.x*256 + threadIdx.x;          // f4 idx in w1: g = o*256+cb
  int o = g >> 8, cb = g & 255;
  float4 v = ((const float4*)w1)[g];
  ((float4*)w1p)[cb*256 + o] = v;
}

// K12: fused part-sum + attention + BN partials. One block per n.
// Phase A (x8 chunks of 128 c-rows): coalesced f4 load of x[n] -> LDS
//   transpose stg[v][row] (stride 129) -> per-row part sums.
//   v-split BY PART boundary (waves 0-1: parts 0-2 / v<27; waves 2-3:
//   parts 3-6 / v>=27) so each half owns COMPLETE part sums: S goes
//   straight into the GEMM LDS array, squared sums stay in registers
//   (q2r[8][4], statically indexed via full unroll). No S/S2 HBM trip.
// Phase B: o x c GEMM (w1p from L2, LDS broadcasts), softmax over parts.
// Phase C: BN partials; sq combines the two halves via a small LDS strip.
// LDS ~64KB -> 2 blocks/CU, all 512 blocks co-resident.
__global__ __launch_bounds__(256) void k12_att(const float* __restrict__ x,
    const float* __restrict__ w1p, const float* __restrict__ b1,
    const float* __restrict__ w2, const float* __restrict__ b2,
    float* __restrict__ att, float* __restrict__ partial){
  int n = blockIdx.x;
  int t = threadIdx.x;

  __shared__ float stg[68*129];                  // 35088 B; reused as hred/sqt
  __shared__ float4 sSf4[PP*256];                // 28672 B: S[p][c] this n
  __shared__ float red_s[4][PP], red_m[4][PP], pre[PP], att_s[PP];
  float* sSl  = (float*)sSf4;                    // [p*1024 + c]
  float* hred = stg;                             // 2048 floats (phase B)
  float* sqt  = stg + 2048;                      // 1024 floats (phase C)

  int row  = t & 127;
  int half = t >> 7;                             // wave-uniform

  float q2r[8][4];                               // per-chunk part sq-sums (regs)
  #pragma unroll
  for (int j=0;j<8;j++){
    q2r[j][0]=0.f; q2r[j][1]=0.f; q2r[j][2]=0.f; q2r[j][3]=0.f;
  }

  const float4* xb = (const float4*)(x + (size_t)n*CC*VV);
  #pragma unroll
  for (int j=0;j<8;j++){
    const float4* src = xb + j*2176;
    #pragma unroll
    for (int k=0;k<9;k++){
      int g = k*256 + t;                         // f4 idx in [0,2176)
      if (k==8 && t>=128) break;
      float4 v4 = src[g];
      int rr = g/17, q = g - rr*17;
      stg[(q*4+0)*129 + rr] = v4.x;
      stg[(q*4+1)*129 + rr] = v4.y;
      stg[(q*4+2)*129 + rr] = v4.z;
      stg[(q*4+3)*129 + rr] = v4.w;
    }
    __syncthreads();
    if (half==0){
      float s[3] = {0.f,0.f,0.f};
      #pragma unroll
      for (int v=0; v<27; v++){
        int p = part_of(v);                      // 0..2, compile-time
        float e = stg[v*129 + row];
        s[p] += e;
        q2r[j][p] = fmaf(e, e, q2r[j][p]);
      }
      #pragma unroll
      for (int p=0;p<3;p++) sSl[p*1024 + j*128 + row] = s[p];
    } else {
      float s[4] = {0.f,0.f,0.f,0.f};
      #pragma unroll
      for (int v=27; v<68; v++){
        int p = part_of(v) - 3;                  // 0..3, compile-time
        float e = stg[v*129 + row];
        s[p] += e;
        q2r[j][p] = fmaf(e, e, q2r[j][p]);
      }
      #pragma unroll
      for (int p=0;p<4;p++) sSl[(p+3)*1024 + j*128 + row] = s[p];
    }
    __syncthreads();                             // stg reads done before next stage
  }

  // ---- Phase B: GEMM acc[k][p] = sum_c S[c,p] * w1[o=k*32+oh, c] ----
  int oh = t & 31, ch = t >> 5;
  float acc[8][PP];
  #pragma unroll
  for (int k=0;k<8;k++)
    #pragma unroll
    for (int p=0;p<PP;p++) acc[k][p] = 0.f;

  const float4* wp = (const float4*)w1p;
  for (int i=0;i<32;i++){
    int gcb = ch*32 + i;
    const float4* wrow = wp + (size_t)gcb*256 + oh;
    float4 w[8];
    #pragma unroll
    for (int k=0;k<8;k++) w[k] = wrow[32*k];
    #pragma unroll
    for (int p=0;p<PP;p++){
      float4 sv = sSf4[p*256 + gcb];             // 2 addrs/wave broadcast
      #pragma unroll
      for (int k=0;k<8;k++){
        acc[k][p] = fmaf(w[k].x, sv.x, acc[k][p]);
        acc[k][p] = fmaf(w[k].y, sv.y, acc[k][p]);
        acc[k][p] = fmaf(w[k].z, sv.z, acc[k][p]);
        acc[k][p] = fmaf(w[k].w, sv.w, acc[k][p]);
      }
    }
  }

  // reduce over ch, mean/max over o, softmax over p
  const float inv_cnt[PP] = {1.f/17.f,1.f/5.f,1.f/5.f,1.f/9.f,1.f/6.f,1.f/6.f,1.f/20.f};
  float bo = b1[t];
  float h[PP];
  #pragma unroll
  for (int p=0;p<PP;p++){
    __syncthreads();
    #pragma unroll
    for (int k=0;k<8;k++) hred[ch*256 + k*32 + oh] = acc[k][p];
    __syncthreads();
    float hs = 0.f;
    #pragma unroll
    for (int c8=0;c8<8;c8++) hs += hred[c8*256 + t];
    h[p] = fmaf(hs, inv_cnt[p], bo);
  }

  int lane = t & 63, wid = t >> 6;
  #pragma unroll
  for (int p=0;p<PP;p++){
    float sm = h[p], mx = h[p];
    #pragma unroll
    for (int off=32; off>0; off>>=1){
      sm += __shfl_down(sm, off, 64);
      mx = fmaxf(mx, __shfl_down(mx, off, 64));
    }
    if (lane==0){ red_s[wid][p]=sm; red_m[wid][p]=mx; }
  }
  __syncthreads();
  if (t < PP){
    int p = t;
    float sm = red_s[0][p]+red_s[1][p]+red_s[2][p]+red_s[3][p];
    float mx = fmaxf(fmaxf(red_m[0][p],red_m[1][p]),
                     fmaxf(red_m[2][p],red_m[3][p]));
    pre[p] = w2[0]*(sm*(1.f/(float)OO)) + w2[1]*mx + b2[0];
  }
  __syncthreads();
  if (t == 0){
    float m = pre[0];
    #pragma unroll
    for (int p=1;p<PP;p++) m = fmaxf(m, pre[p]);
    float e[PP], sum=0.f;
    #pragma unroll
    for (int p=0;p<PP;p++){ e[p] = expf(pre[p]-m); sum += e[p]; }
    float inv = 1.f/sum;
    #pragma unroll
    for (int p=0;p<PP;p++){
      float a = e[p]*inv;
      att_s[p] = a;
      att[n*PP+p] = a;
    }
  }
  __syncthreads();

  // ---- Phase C: BN partials ----
  float a[PP];
  #pragma unroll
  for (int p=0;p<PP;p++) a[p] = att_s[p];

  // sm partials: all 256 threads, from LDS S
  #pragma unroll
  for (int jj=0;jj<4;jj++){
    int c = jj*256 + t;
    float sm = 0.f;
    #pragma unroll
    for (int p=0;p<PP;p++) sm = fmaf(a[p], sSl[p*1024 + c], sm);
    partial[n*2048 + c] = sm;
  }

  // sq partials: combine the two halves' register sq-sums via LDS strip
  if (half==1){
    #pragma unroll
    for (int j=0;j<8;j++){
      float sq = 0.f;
      #pragma unroll
      for (int p=0;p<4;p++){
        float ap = a[p+3];
        sq = fmaf(ap*ap, q2r[j][p], sq);
      }
      sqt[j*128 + row] = sq;
    }
  }
  __syncthreads();
  if (half==0){
    #pragma unroll
    for (int j=0;j<8;j++){
      float sq = sqt[j*128 + row];
      #pragma unroll
      for (int p=0;p<3;p++){
        float ap = a[p];
        sq = fmaf(ap*ap, q2r[j][p], sq);
      }
      partial[n*2048 + 1024 + j*128 + row] = sq;
    }
  }
}

// K3b: single-dispatch reduce over n + BN finalize. 32 blocks x 256 thr.
__global__ __launch_bounds__(256) void k3b_finalize(const float* __restrict__ partial,
    const float* __restrict__ gamma, const float* __restrict__ beta,
    float* __restrict__ scsh){
  __shared__ float rs[8][32], rq[8][32];
  int cl = threadIdx.x & 31, grp = threadIdx.x >> 5;
  int c = blockIdx.x*32 + cl;
  float sm=0.f, sq=0.f;
  for (int i=0;i<64;i++){
    int n = grp*64 + i;
    sm += partial[n*2048 + c];
    sq += partial[n*2048 + 1024 + c];
  }
  rs[grp][cl] = sm; rq[grp][cl] = sq;
  __syncthreads();
  if (threadIdx.x < 32){
    float tsm=0.f, tsq=0.f;
    #pragma unroll
    for (int g=0; g<8; g++){ tsm += rs[g][threadIdx.x]; tsq += rq[g][threadIdx.x]; }
    int cc = blockIdx.x*32 + threadIdx.x;
    float mean = tsm * (1.0f/NV_CNT);
    float var  = tsq * (1.0f/NV_CNT) - mean*mean;
    float rstd = rsqrtf(var + 1e-5f);
    float sc = gamma[cc]*rstd;
    scsh[cc]        = sc;
    scsh[1024 + cc] = beta[cc] - mean*sc;
  }
}

// K4: out = relu( x*(att_j*sc + 1) + sh ); nontemporal stores via ext_vector.
__global__ __launch_bounds__(256) void k4_out(const float* __restrict__ x,
    const float* __restrict__ att, const float* __restrict__ scsh,
    float* __restrict__ out){
  int f = blockIdx.x*256 + threadIdx.x;          // float4 index, < NC*17
  int n = blockIdx.x / 68;                       // uniform within block
  __shared__ float s_att[PP];
  if (threadIdx.x < PP) s_att[threadIdx.x] = att[n*PP + threadIdx.x];
  __syncthreads();
  int r = f/17;
  int q = f - r*17;
  int v0 = q*4;
  int c = r & (CC-1);
  float4 xv = ((const float4*)x)[f];
  float sc = scsh[c];
  float sh = scsh[1024 + c];
  float vals[4];
  #pragma unroll
  for (int j=0;j<4;j++){
    int p = part_of(v0 + j);
    float a = s_att[p];
    float e = (j==0)?xv.x:(j==1)?xv.y:(j==2)?xv.z:xv.w;
    vals[j] = fmaxf(fmaf(e, fmaf(a, sc, 1.0f), sh), 0.0f);
  }
  floatx4 ov; ov.x=vals[0]; ov.y=vals[1]; ov.z=vals[2]; ov.w=vals[3];
  __builtin_nontemporal_store(ov, ((floatx4*)out) + f);
}

extern "C" void kernel_launch(void* const* d_in, const int* in_sizes, int n_in,
                              void* d_out, int out_size, void* d_ws, size_t ws_size,
                              hipStream_t stream) {
  const float* x     = (const float*)d_in[0];
  const float* w1    = (const float*)d_in[1];
  const float* b1    = (const float*)d_in[2];
  const float* w2    = (const float*)d_in[3];
  const float* b2    = (const float*)d_in[4];
  const float* gamma = (const float*)d_in[5];
  const float* beta  = (const float*)d_in[6];
  float* out = (float*)d_out;

  float* w1p     = (float*)d_ws;                 // 256*1024 (1 MB)
  float* partial = w1p + OO*CC;                  // 512*2048 (4 MB)
  float* scsh    = partial + NN*2048;            // 2048
  float* att     = scsh + 2048;                  // 512*7
  // ~5 MB of ws; every buffer fully overwritten each call

  k0_prep     <<<256,         256, 0, stream>>>(w1, w1p);
  k12_att     <<<NN,          256, 0, stream>>>(x, w1p, b1, w2, b2, att, partial);
  k3b_finalize<<<32,          256, 0, stream>>>(partial, gamma, beta, scsh);
  k4_out      <<<(NC*17)/256, 256, 0, stream>>>(x, att, scsh, out);
}